// Round 4
// baseline (398.532 us; speedup 1.0000x reference)
//
#include <hip/hip_runtime.h>
#include <hip/hip_bf16.h>

typedef __bf16 bf16x8 __attribute__((ext_vector_type(8)));
typedef float f32x4 __attribute__((ext_vector_type(4)));
typedef unsigned short u16;
typedef unsigned short us4 __attribute__((ext_vector_type(4)));
typedef unsigned int u32;

// ---------- bf16 helpers (RNE) ----------
__device__ __forceinline__ u16 f2bf(float x) {
  union { float f; u32 u; } v; v.f = x;
  u32 r = v.u + 0x7FFFu + ((v.u >> 16) & 1u);
  return (u16)(r >> 16);
}
__device__ __forceinline__ float bf2f(u16 h) {
  union { u32 u; float f; } v; v.u = ((u32)h) << 16;
  return v.f;
}

__device__ __forceinline__ void glds16(const void* g, void* l) {
  __builtin_amdgcn_global_load_lds(
      (const __attribute__((address_space(1))) void*)g,
      (__attribute__((address_space(3))) void*)l, 16, 0, 0);
}

#define BARRIER_FENCED() do {                        \
  __builtin_amdgcn_sched_barrier(0);                 \
  __builtin_amdgcn_s_barrier();                      \
  __builtin_amdgcn_sched_barrier(0);                 \
} while (0)

// ---------- universal B^T GEMM: C[M,N] = A[M,K] * B[N,K]^T ----------
// BM=256, BN=128, BK=64. 8 waves = 2M x 2N x 2Ksplit; per-wave 128x64 output.
// LDS fragment-packed (1KB contiguous per 16x32 fragment in MFMA lane order;
// conflict-free reads, verified BANK_CONFLICT=0). 3-buffer, 2-tiles-ahead
// pipeline, counted vmcnt(6) once per tile (never 0 in steady state).
// K-loop = 4 fine phases per tile (m196/m201 lever): each phase
// {ds_read subtile + 2 glds of tile t+2} -> barrier -> lgkmcnt(0) ->
// setprio(1) 8 MFMA setprio(0) -> barrier.
// NSEG==3: A,B packed [hi|lo] (ld=2*K0, K0==1024): Ah*Bh + Al*Bh + Ah*Bl.
// EPI: 0 = fp32 store; 1 = +bias, hi/lo bf16 split store; 2 = bf16 store;
//      3 = +bias, tanh, fp32 store.
template<int NSEG, int EPI>
__global__ __launch_bounds__(512, 2)
void gemm_bt(const u16* __restrict__ A, const u16* __restrict__ B,
             void* __restrict__ Cout, const float* __restrict__ bias,
             int K0, int lda, int ldb, int ldc,
             long sA, long sB, long sC, int nx, int ny)
{
  // 3 buffers x (A 32KB frag-packed + B 16KB) = 144KB
  __shared__ __align__(1024) char lds_raw[3 * 49152];

  // bijective XCD-chunk swizzle (nwg=256, 8 XCDs, 32-block chunks)
  const int d = blockIdx.x;
  const int L = ((d & 7) << 5) | (d >> 3);
  const int nxy = nx * ny;
  const int bz = L / nxy;
  const int rr = L - bz * nxy;
  const int bx = rr / ny;
  const int by = rr - bx * ny;
  const int brow = bx * 256;
  const int bcol = by * 128;

  const int tid  = threadIdx.x;
  const int wid  = tid >> 6;       // 0..7
  const int lane = tid & 63;
  const int kh   = wid >> 2;       // k-split half 0/1
  const int wr   = (wid >> 1) & 1; // 128-row group
  const int wc   = wid & 1;        // 64-col group

  const u16* Ab = A + (long)bz * sA + (long)brow * lda;
  const u16* Bb = B + (long)bz * sB + (long)bcol * ldb;

  f32x4 acc[8][4];
#pragma unroll
  for (int m = 0; m < 8; ++m)
#pragma unroll
    for (int n = 0; n < 4; ++n) acc[m][n] = (f32x4){0.f, 0.f, 0.f, 0.f};

  const int ksteps = (NSEG == 3) ? 16 : (K0 >> 6);
  const int NT = NSEG * ksteps;

  // per-lane fragment-source offsets (MFMA A/B layout: row=lane&15, k=(lane>>4)*8)
  const int r15 = lane & 15;
  const int c16 = (lane >> 4) * 8;

  auto srcAB = [&](int t, const u16*& Aseg, const u16*& Bseg) {
    int seg, kt;
    if (NSEG == 3) { seg = t >> 4; kt = (t & 15) << 6; }
    else           { seg = 0;      kt = t << 6; }
    Aseg = Ab + ((NSEG == 3 && seg == 1) ? K0 : 0) + kt;
    Bseg = Bb + ((NSEG == 3 && seg == 2) ? K0 : 0) + kt;
  };
  // wave wid stages A frags wid*4..+3 (two pairs) and B frags wid*2..+1
  auto stageA = [&](const u16* Aseg, u16* Lb, int q0) {
#pragma unroll
    for (int q = q0; q < q0 + 2; ++q) {
      const int fa = wid * 4 + q;
      const int mi = fa >> 1, ki = fa & 1;
      glds16(Aseg + (long)(mi * 16 + r15) * lda + ki * 32 + c16, Lb + fa * 512);
    }
  };
  auto stageB = [&](const u16* Bseg, u16* Lb) {
#pragma unroll
    for (int q = 0; q < 2; ++q) {
      const int fb = wid * 2 + q;
      const int nj = fb >> 1, ki = fb & 1;
      glds16(Bseg + (long)(nj * 16 + r15) * ldb + ki * 32 + c16,
             Lb + 16384 + fb * 512);
    }
  };

  // prologue: fill tiles 0 and 1, wait for tile 0 (6 of 12 loads)
  {
    const u16 *A0, *B0, *A1, *B1;
    srcAB(0, A0, B0);
    srcAB(1, A1, B1);
    u16* L0 = (u16*)lds_raw;
    u16* L1 = (u16*)(lds_raw + 49152);
    stageA(A0, L0, 0); stageA(A0, L0, 2); stageB(B0, L0);
    stageA(A1, L1, 0); stageA(A1, L1, 2); stageB(B1, L1);
  }
  asm volatile("s_waitcnt vmcnt(6)" ::: "memory");
  BARRIER_FENCED();

  int bufc = 0;
  for (int t = 0; t < NT; ++t) {
    const u16* Lb = (const u16*)(lds_raw + bufc * 49152);
    const u16* Af = Lb + (wr * 16 + kh) * 512 + lane * 8;        // frag (wr*8+m)*2+kh
    const u16* Bf = Lb + 16384 + (wc * 8 + kh) * 512 + lane * 8; // frag (wc*4+n)*2+kh

    const bool pre = (t + 2 < NT);
    const u16 *Asg = nullptr, *Bsg = nullptr;
    u16* Ls = nullptr;
    if (pre) {
      srcAB(t + 2, Asg, Bsg);
      int bufs = bufc + 2; if (bufs >= 3) bufs -= 3;
      Ls = (u16*)(lds_raw + bufs * 49152);
    }

    bf16x8 bfr[4];

    // ---- phase 0: read b0..b3,a0,a1; stage A-part0; MFMA m=0,1 ----
    {
      bf16x8 a0 = *(const bf16x8*)(Af + 0 * 1024);
      bf16x8 a1 = *(const bf16x8*)(Af + 1 * 1024);
#pragma unroll
      for (int n = 0; n < 4; ++n) bfr[n] = *(const bf16x8*)(Bf + n * 1024);
      if (pre) stageA(Asg, Ls, 0);
      BARRIER_FENCED();
      asm volatile("s_waitcnt lgkmcnt(0)" ::: "memory");
      __builtin_amdgcn_sched_barrier(0);
      __builtin_amdgcn_s_setprio(1);
#pragma unroll
      for (int n = 0; n < 4; ++n) {
        acc[0][n] = __builtin_amdgcn_mfma_f32_16x16x32_bf16(a0, bfr[n], acc[0][n], 0, 0, 0);
        acc[1][n] = __builtin_amdgcn_mfma_f32_16x16x32_bf16(a1, bfr[n], acc[1][n], 0, 0, 0);
      }
      __builtin_amdgcn_s_setprio(0);
      BARRIER_FENCED();
    }
    // ---- phase 1: read a2,a3; stage A-part1; MFMA m=2,3 ----
    {
      bf16x8 a2 = *(const bf16x8*)(Af + 2 * 1024);
      bf16x8 a3 = *(const bf16x8*)(Af + 3 * 1024);
      if (pre) stageA(Asg, Ls, 2);
      BARRIER_FENCED();
      asm volatile("s_waitcnt lgkmcnt(0)" ::: "memory");
      __builtin_amdgcn_sched_barrier(0);
      __builtin_amdgcn_s_setprio(1);
#pragma unroll
      for (int n = 0; n < 4; ++n) {
        acc[2][n] = __builtin_amdgcn_mfma_f32_16x16x32_bf16(a2, bfr[n], acc[2][n], 0, 0, 0);
        acc[3][n] = __builtin_amdgcn_mfma_f32_16x16x32_bf16(a3, bfr[n], acc[3][n], 0, 0, 0);
      }
      __builtin_amdgcn_s_setprio(0);
      BARRIER_FENCED();
    }
    // ---- phase 2: read a4,a5; stage B-part; MFMA m=4,5 ----
    {
      bf16x8 a4 = *(const bf16x8*)(Af + 4 * 1024);
      bf16x8 a5 = *(const bf16x8*)(Af + 5 * 1024);
      if (pre) stageB(Bsg, Ls);
      BARRIER_FENCED();
      asm volatile("s_waitcnt lgkmcnt(0)" ::: "memory");
      __builtin_amdgcn_sched_barrier(0);
      __builtin_amdgcn_s_setprio(1);
#pragma unroll
      for (int n = 0; n < 4; ++n) {
        acc[4][n] = __builtin_amdgcn_mfma_f32_16x16x32_bf16(a4, bfr[n], acc[4][n], 0, 0, 0);
        acc[5][n] = __builtin_amdgcn_mfma_f32_16x16x32_bf16(a5, bfr[n], acc[5][n], 0, 0, 0);
      }
      __builtin_amdgcn_s_setprio(0);
      BARRIER_FENCED();
    }
    // ---- phase 3: read a6,a7; MFMA m=6,7; counted vmcnt; tile-end barrier ----
    {
      bf16x8 a6 = *(const bf16x8*)(Af + 6 * 1024);
      bf16x8 a7 = *(const bf16x8*)(Af + 7 * 1024);
      BARRIER_FENCED();
      asm volatile("s_waitcnt lgkmcnt(0)" ::: "memory");
      __builtin_amdgcn_sched_barrier(0);
      __builtin_amdgcn_s_setprio(1);
#pragma unroll
      for (int n = 0; n < 4; ++n) {
        acc[6][n] = __builtin_amdgcn_mfma_f32_16x16x32_bf16(a6, bfr[n], acc[6][n], 0, 0, 0);
        acc[7][n] = __builtin_amdgcn_mfma_f32_16x16x32_bf16(a7, bfr[n], acc[7][n], 0, 0, 0);
      }
      __builtin_amdgcn_s_setprio(0);
      if (pre) { asm volatile("s_waitcnt vmcnt(6)" ::: "memory"); }
      else     { asm volatile("s_waitcnt vmcnt(0)" ::: "memory"); }
      BARRIER_FENCED();
    }
    bufc = bufc + 1; if (bufc >= 3) bufc = 0;
  }

  // ---- k-split reduction through LDS (reuses buffers; all tiles consumed) ----
  float* red = (float*)lds_raw;
  const int p = wr * 2 + wc;
  if (kh == 1) {
#pragma unroll
    for (int m = 0; m < 8; ++m)
#pragma unroll
      for (int n = 0; n < 4; ++n)
        *(f32x4*)(red + ((p * 32 + m * 4 + n) * 64 + lane) * 4) = acc[m][n];
  }
  asm volatile("s_waitcnt lgkmcnt(0)" ::: "memory");
  BARRIER_FENCED();

  if (kh == 0) {
#pragma unroll
    for (int m = 0; m < 8; ++m)
#pragma unroll
      for (int n = 0; n < 4; ++n)
        acc[m][n] += *(const f32x4*)(red + ((p * 32 + m * 4 + n) * 64 + lane) * 4);

    // epilogue: C/D layout col=lane&15, row=(lane>>4)*4+reg [m89-verified]
    const int crow0 = brow + wr * 128;
    const int ccol0 = bcol + wc * 64;
    const int orow  = (lane >> 4) * 4;
    const int ocol  = lane & 15;
#pragma unroll
    for (int m = 0; m < 8; ++m) {
#pragma unroll
      for (int n = 0; n < 4; ++n) {
        const int col = ccol0 + n * 16 + ocol;
        float bv = 0.f;
        if (EPI == 1 || EPI == 3) bv = bias[col];
#pragma unroll
        for (int j = 0; j < 4; ++j) {
          const int row = crow0 + m * 16 + orow + j;
          float v = acc[m][n][j] + bv;
          if (EPI == 0) {
            ((float*)Cout)[(long)bz * sC + (long)row * ldc + col] = v;
          } else if (EPI == 1) {
            u16 hi = f2bf(v);
            u16 lo = f2bf(v - bf2f(hi));
            u16* Co = (u16*)Cout + (long)bz * sC + (long)row * ldc;
            Co[col] = hi;
            Co[col + 1024] = lo;
          } else if (EPI == 2) {
            ((u16*)Cout)[(long)bz * sC + (long)row * ldc + col] = f2bf(v);
          } else {
            ((float*)Cout)[(long)bz * sC + (long)row * ldc + col] = tanhf(v);
          }
        }
      }
    }
  }
}

// ---------- fp32 -> [hi|lo] bf16 pack (rows x 1024 -> rows x 2048) ----------
__global__ __launch_bounds__(256)
void split_pack(const float* __restrict__ X, u16* __restrict__ P,
                u16* __restrict__ FQ, long n4)
{
  long i = (long)blockIdx.x * 256 + threadIdx.x;
  const long stride = (long)gridDim.x * 256;
  for (; i < n4; i += stride) {
    float4 x = ((const float4*)X)[i];
    long e = i * 4;
    long row = e >> 10;
    int col = (int)(e & 1023);
    float xs[4] = {x.x, x.y, x.z, x.w};
    u16 h[4], l[4];
#pragma unroll
    for (int j = 0; j < 4; ++j) {
      h[j] = f2bf(xs[j]);
      l[j] = f2bf(xs[j] - bf2f(h[j]));
    }
    us4 hv = {h[0], h[1], h[2], h[3]};
    us4 lv = {l[0], l[1], l[2], l[3]};
    *(us4*)(P + row * 2048 + col) = hv;
    *(us4*)(P + row * 2048 + 1024 + col) = lv;
    if (FQ) *(us4*)(FQ + row * 2048 + 1024 + col) = hv;
  }
}

// ---------- values: [hi|lo] pack (row-major) + bf16 transpose ----------
__global__ __launch_bounds__(256)
void conv_values(const float* __restrict__ V, u16* __restrict__ Vp,
                 u16* __restrict__ VT)
{
  __shared__ u16 tile[64][68];
  const int b  = blockIdx.z;
  const int d0 = blockIdx.x * 64;
  const int k0 = blockIdx.y * 64;
  const int t  = threadIdx.x;
  const int tr = t >> 4;            // 0..15
  const int tc = (t & 15) * 4;      // 0..60
  const float* Vb = V + (long)b * (1024L * 1024);
  u16* Vpb = Vp + (long)b * (1024L * 2048);
  u16* VTb = VT + (long)b * (1024L * 1024);

#pragma unroll
  for (int i = 0; i < 4; ++i) {
    int k = tr + i * 16;
    float4 x = *(const float4*)(Vb + (long)(k0 + k) * 1024 + d0 + tc);
    float xs[4] = {x.x, x.y, x.z, x.w};
    u16 h[4], l[4];
#pragma unroll
    for (int j = 0; j < 4; ++j) {
      h[j] = f2bf(xs[j]);
      l[j] = f2bf(xs[j] - bf2f(h[j]));
      tile[k][tc + j] = h[j];
    }
    us4 hv = {h[0], h[1], h[2], h[3]};
    us4 lv = {l[0], l[1], l[2], l[3]};
    *(us4*)(Vpb + (long)(k0 + k) * 2048 + d0 + tc) = hv;
    *(us4*)(Vpb + (long)(k0 + k) * 2048 + 1024 + d0 + tc) = lv;
  }
  __syncthreads();
#pragma unroll
  for (int i = 0; i < 4; ++i) {
    int d = tr + i * 16;
    int k = tc;
    us4 o = {tile[k][d], tile[k + 1][d], tile[k + 2][d], tile[k + 3][d]};
    *(us4*)(VTb + (long)(d0 + d) * 1024 + k0 + k) = o;
  }
}

// ---------- plain fp32 -> bf16 cast ----------
__global__ __launch_bounds__(256)
void conv_cast(const float* __restrict__ X, u16* __restrict__ Y, long n4)
{
  long i = (long)blockIdx.x * 256 + threadIdx.x;
  const long stride = (long)gridDim.x * 256;
  for (; i < n4; i += stride) {
    float4 x = ((const float4*)X)[i];
    us4 o = {f2bf(x.x), f2bf(x.y), f2bf(x.z), f2bf(x.w)};
    *(us4*)(Y + i * 4) = o;
  }
}

// ---------- row softmax: fp32 scores[8192][1024] -> bf16 attn ----------
__global__ __launch_bounds__(256)
void softmax_rows(const float* __restrict__ S, u16* __restrict__ A)
{
  const long row = blockIdx.x;
  const float* src = S + row * 1024;
  const int t = threadIdx.x;
  const int lane = t & 63, wid = t >> 6;
  float4 v = ((const float4*)src)[t];
  float m = fmaxf(fmaxf(v.x, v.y), fmaxf(v.z, v.w));
#pragma unroll
  for (int off = 32; off >= 1; off >>= 1)
    m = fmaxf(m, __shfl_xor(m, off));
  __shared__ float redm[4];
  if (lane == 0) redm[wid] = m;
  __syncthreads();
  m = fmaxf(fmaxf(redm[0], redm[1]), fmaxf(redm[2], redm[3]));
  float e0 = __expf(v.x - m), e1 = __expf(v.y - m);
  float e2 = __expf(v.z - m), e3 = __expf(v.w - m);
  float s = e0 + e1 + e2 + e3;
#pragma unroll
  for (int off = 32; off >= 1; off >>= 1)
    s += __shfl_xor(s, off);
  __shared__ float reds[4];
  if (lane == 0) reds[wid] = s;
  __syncthreads();
  s = reds[0] + reds[1] + reds[2] + reds[3];
  float inv = 1.0f / s;
  us4 o = {f2bf(e0 * inv), f2bf(e1 * inv), f2bf(e2 * inv), f2bf(e3 * inv)};
  ((us4*)(A + row * 1024))[t] = o;
}

extern "C" void kernel_launch(void* const* d_in, const int* in_sizes, int n_in,
                              void* d_out, int out_size, void* d_ws, size_t ws_size,
                              hipStream_t stream)
{
  const float* query  = (const float*)d_in[0];  // [8,1024,1024]
  const float* values = (const float*)d_in[1];  // [8,1024,1024]
  const float* W1     = (const float*)d_in[2];  // [1024,1024]
  const float* b1     = (const float*)d_in[3];  // [1024]
  const float* W2     = (const float*)d_in[4];  // [1024,2048]
  const float* b2     = (const float*)d_in[5];  // [1024]
  float* out = (float*)d_out;                   // [8,1024,1024]

  char* ws = (char*)d_ws;
  const long MB = 1024L * 1024;
  // layout (152 MB total, with lifetime aliasing):
  u16*   W1p    = (u16*)(ws);              //   4 MB  W1 [hi|lo]
  u16*   W2b    = (u16*)(ws + 4 * MB);     //   4 MB  W2 bf16
  u16*   Aq     = (u16*)(ws + 8 * MB);     //  32 MB  query [hi|lo]   (dead after GEMM1)
  float* scores = (float*)(ws + 8 * MB);   //  32 MB  aliases Aq
  u16*   qr     = (u16*)(ws + 40 * MB);    //  32 MB  q_resize [hi|lo] (dead after GEMM2)
  u16*   attn   = (u16*)(ws + 40 * MB);    //  16 MB  aliases qr
  u16*   Vp     = (u16*)(ws + 72 * MB);    //  32 MB  values [hi|lo]
  u16*   VT     = (u16*)(ws + 104 * MB);   //  16 MB  values^T bf16
  u16*   feed   = (u16*)(ws + 120 * MB);   //  32 MB  [attended | query] bf16

  // conversions
  split_pack<<<dim3(2048), dim3(256), 0, stream>>>(query, Aq, feed, (8192L * 1024) / 4);
  split_pack<<<dim3(1024), dim3(256), 0, stream>>>(W1, W1p, (u16*)nullptr, (1024L * 1024) / 4);
  conv_values<<<dim3(16, 16, 8), dim3(256), 0, stream>>>(values, Vp, VT);
  conv_cast<<<dim3(1024), dim3(256), 0, stream>>>(W2, W2b, (1024L * 2048) / 4);

  // GEMM1: q_resize = query @ W1^T + b1  -> qr [hi|lo]   (hi/lo, virt-K=3072)
  gemm_bt<3, 1><<<dim3(256), dim3(512), 0, stream>>>(
      Aq, W1p, qr, b1, 1024, 2048, 2048, 2048, 0L, 0L, 0L, 32, 8);

  // GEMM2: scores[b] = qr[b] @ values[b]^T               (hi/lo, batched)
  gemm_bt<3, 0><<<dim3(256), dim3(512), 0, stream>>>(
      qr, Vp, scores, (const float*)nullptr, 1024, 2048, 2048, 1024,
      1024L * 2048, 1024L * 2048, 1024L * 1024, 4, 8);

  // softmax over keys -> bf16 attn
  softmax_rows<<<dim3(8192), dim3(256), 0, stream>>>(scores, attn);

  // GEMM3: attended[b] = attn[b] @ values[b] -> feed[:, 0:1024] bf16
  gemm_bt<1, 2><<<dim3(256), dim3(512), 0, stream>>>(
      attn, VT, feed, (const float*)nullptr, 1024, 1024, 1024, 2048,
      1024L * 1024, 1024L * 1024, 1024L * 2048, 4, 8);

  // GEMM4: out = tanh(feed @ W2^T + b2)
  gemm_bt<1, 3><<<dim3(256), dim3(512), 0, stream>>>(
      feed, W2b, out, b2, 2048, 2048, 2048, 1024, 0L, 0L, 0L, 32, 8);
}

// Round 5
// 378.054 us; speedup vs baseline: 1.0542x; 1.0542x over previous
//
#include <hip/hip_runtime.h>
#include <hip/hip_bf16.h>

typedef __bf16 bf16x8 __attribute__((ext_vector_type(8)));
typedef float f32x4 __attribute__((ext_vector_type(4)));
typedef unsigned short u16;
typedef unsigned short us4 __attribute__((ext_vector_type(4)));
typedef unsigned int u32;

// ---------- bf16 helpers (RNE) ----------
__device__ __forceinline__ u16 f2bf(float x) {
  union { float f; u32 u; } v; v.f = x;
  u32 r = v.u + 0x7FFFu + ((v.u >> 16) & 1u);
  return (u16)(r >> 16);
}
__device__ __forceinline__ float bf2f(u16 h) {
  union { u32 u; float f; } v; v.u = ((u32)h) << 16;
  return v.f;
}

__device__ __forceinline__ void glds16(const void* g, void* l) {
  __builtin_amdgcn_global_load_lds(
      (const __attribute__((address_space(1))) void*)g,
      (__attribute__((address_space(3))) void*)l, 16, 0, 0);
}

#define BARRIER_FENCED() do {                        \
  __builtin_amdgcn_sched_barrier(0);                 \
  __builtin_amdgcn_s_barrier();                      \
  __builtin_amdgcn_sched_barrier(0);                 \
} while (0)

// ---------- universal B^T GEMM: C[M,N] = A[M,K] * B[N,K]^T ----------
// BM=256, BN=128, BK=64. 8 waves = 4M x 2N; per-wave 64x64 (acc 4x4).
// LDS fragment-packed (1KB per 16x32 fragment in MFMA lane order; verified
// BANK_CONFLICT=0). 3-buffer, 2-tiles-ahead pipeline, counted vmcnt(6).
// K-loop = 2 phases per tile (phase = k-half), m201 density: each phase
// {8 ds_read_b128 + 3 glds} -> barrier -> lgkmcnt(0) -> setprio(1) ->
// 16 MFMA -> setprio(0) -> barrier.
// NSEG==3: A,B packed [hi|lo] (ld=2*K0, K0==1024): Ah*Bh + Al*Bh + Ah*Bl.
// EPI: 0 = fp32 store; 1 = +bias, hi/lo bf16 split store; 2 = bf16 store;
//      3 = +bias, tanh, fp32 store.
template<int NSEG, int EPI>
__global__ __launch_bounds__(512, 2)
void gemm_bt(const u16* __restrict__ A, const u16* __restrict__ B,
             void* __restrict__ Cout, const float* __restrict__ bias,
             int K0, int lda, int ldb, int ldc,
             long sA, long sB, long sC, int nx, int ny)
{
  // 3 buffers x (A 32KB frag-packed + B 16KB) = 144KB
  __shared__ __align__(1024) char lds_raw[3 * 49152];

  // bijective XCD-chunk swizzle (nwg=256, 8 XCDs, 32-block chunks)
  const int d = blockIdx.x;
  const int L = ((d & 7) << 5) | (d >> 3);
  const int nxy = nx * ny;
  const int bz = L / nxy;
  const int rr = L - bz * nxy;
  const int bx = rr / ny;
  const int by = rr - bx * ny;
  const int brow = bx * 256;
  const int bcol = by * 128;

  const int tid  = threadIdx.x;
  const int wid  = tid >> 6;       // 0..7
  const int lane = tid & 63;
  const int wr   = wid >> 1;       // 0..3  (64-row block)
  const int wc   = wid & 1;        // 0..1  (64-col block)

  const u16* Ab = A + (long)bz * sA + (long)brow * lda;
  const u16* Bb = B + (long)bz * sB + (long)bcol * ldb;

  f32x4 acc[4][4];
#pragma unroll
  for (int m = 0; m < 4; ++m)
#pragma unroll
    for (int n = 0; n < 4; ++n) acc[m][n] = (f32x4){0.f, 0.f, 0.f, 0.f};

  const int ksteps = (NSEG == 3) ? 16 : (K0 >> 6);
  const int NT = NSEG * ksteps;

  // per-lane fragment-source offsets (MFMA A/B layout: row=lane&15, k=(lane>>4)*8)
  const int r15 = lane & 15;
  const int c16 = (lane >> 4) * 8;

  auto srcAB = [&](int t, const u16*& Aseg, const u16*& Bseg) {
    int seg, kt;
    if (NSEG == 3) { seg = t >> 4; kt = (t & 15) << 6; }
    else           { seg = 0;      kt = t << 6; }
    Aseg = Ab + ((NSEG == 3 && seg == 1) ? K0 : 0) + kt;
    Bseg = Bb + ((NSEG == 3 && seg == 2) ? K0 : 0) + kt;
  };
  // A: 32 frags fa=mi*2+ki (mi=row/16, ki=k-half); wave stages fa=wid*4..+3
  auto stageA = [&](const u16* Aseg, u16* Lb, int q0) {
#pragma unroll
    for (int q = q0; q < q0 + 2; ++q) {
      const int fa = wid * 4 + q;
      const int mi = fa >> 1, ki = fa & 1;
      glds16(Aseg + (long)(mi * 16 + r15) * lda + ki * 32 + c16, Lb + fa * 512);
    }
  };
  // B: 16 frags fb=nj*2+ki (nj=col/16); wave stages fb=wid*2+q
  auto stageB = [&](const u16* Bseg, u16* Lb, int q) {
    const int fb = wid * 2 + q;
    const int nj = fb >> 1, ki = fb & 1;
    glds16(Bseg + (long)(nj * 16 + r15) * ldb + ki * 32 + c16,
           Lb + 16384 + fb * 512);
  };

  // prologue: fill tiles 0 and 1, wait for tile 0 (6 of 12 loads)
  {
    const u16 *A0, *B0, *A1, *B1;
    srcAB(0, A0, B0);
    srcAB(1, A1, B1);
    u16* L0 = (u16*)lds_raw;
    u16* L1 = (u16*)(lds_raw + 49152);
    stageA(A0, L0, 0); stageA(A0, L0, 2); stageB(B0, L0, 0); stageB(B0, L0, 1);
    stageA(A1, L1, 0); stageA(A1, L1, 2); stageB(B1, L1, 0); stageB(B1, L1, 1);
  }
  asm volatile("s_waitcnt vmcnt(6)" ::: "memory");
  BARRIER_FENCED();

  int bufc = 0;
  for (int t = 0; t < NT; ++t) {
    const u16* Lb = (const u16*)(lds_raw + bufc * 49152);
    // per-wave fragment bases: A frag (wr*4+m)*2+kh ; B frag (wc*4+n)*2+kh
    const u16* Af = Lb + (wr * 8) * 512 + lane * 8;
    const u16* Bf = Lb + 16384 + (wc * 8) * 512 + lane * 8;

    const bool pre = (t + 2 < NT);
    const u16 *Asg = nullptr, *Bsg = nullptr;
    u16* Ls = nullptr;
    if (pre) {
      srcAB(t + 2, Asg, Bsg);
      int bufs = bufc + 2; if (bufs >= 3) bufs -= 3;
      Ls = (u16*)(lds_raw + bufs * 49152);
    }

    // ---- phase 0 (k-half 0): 8 ds_read + 3 glds; 16 MFMA ----
    {
      bf16x8 a[4], b[4];
#pragma unroll
      for (int m = 0; m < 4; ++m) a[m] = *(const bf16x8*)(Af + (m * 2 + 0) * 512);
#pragma unroll
      for (int n = 0; n < 4; ++n) b[n] = *(const bf16x8*)(Bf + (n * 2 + 0) * 512);
      if (pre) { stageA(Asg, Ls, 0); stageB(Bsg, Ls, 0); }
      BARRIER_FENCED();
      asm volatile("s_waitcnt lgkmcnt(0)" ::: "memory");
      __builtin_amdgcn_sched_barrier(0);
      __builtin_amdgcn_s_setprio(1);
#pragma unroll
      for (int m = 0; m < 4; ++m)
#pragma unroll
        for (int n = 0; n < 4; ++n)
          acc[m][n] = __builtin_amdgcn_mfma_f32_16x16x32_bf16(a[m], b[n], acc[m][n], 0, 0, 0);
      __builtin_amdgcn_s_setprio(0);
      BARRIER_FENCED();
    }
    // ---- phase 1 (k-half 1): 8 ds_read + 3 glds; 16 MFMA; counted vmcnt ----
    {
      bf16x8 a[4], b[4];
#pragma unroll
      for (int m = 0; m < 4; ++m) a[m] = *(const bf16x8*)(Af + (m * 2 + 1) * 512);
#pragma unroll
      for (int n = 0; n < 4; ++n) b[n] = *(const bf16x8*)(Bf + (n * 2 + 1) * 512);
      if (pre) { stageA(Asg, Ls, 2); stageB(Bsg, Ls, 1); }
      BARRIER_FENCED();
      asm volatile("s_waitcnt lgkmcnt(0)" ::: "memory");
      __builtin_amdgcn_sched_barrier(0);
      __builtin_amdgcn_s_setprio(1);
#pragma unroll
      for (int m = 0; m < 4; ++m)
#pragma unroll
        for (int n = 0; n < 4; ++n)
          acc[m][n] = __builtin_amdgcn_mfma_f32_16x16x32_bf16(a[m], b[n], acc[m][n], 0, 0, 0);
      __builtin_amdgcn_s_setprio(0);
      if (pre) { asm volatile("s_waitcnt vmcnt(6)" ::: "memory"); }
      else     { asm volatile("s_waitcnt vmcnt(0)" ::: "memory"); }
      BARRIER_FENCED();
    }
    bufc = bufc + 1; if (bufc >= 3) bufc = 0;
  }

  // epilogue: C/D layout col=lane&15, row=(lane>>4)*4+reg [m89-verified]
  const int crow0 = brow + wr * 64;
  const int ccol0 = bcol + wc * 64;
  const int orow  = (lane >> 4) * 4;
  const int ocol  = lane & 15;
#pragma unroll
  for (int m = 0; m < 4; ++m) {
#pragma unroll
    for (int n = 0; n < 4; ++n) {
      const int col = ccol0 + n * 16 + ocol;
      float bv = 0.f;
      if (EPI == 1 || EPI == 3) bv = bias[col];
#pragma unroll
      for (int j = 0; j < 4; ++j) {
        const int row = crow0 + m * 16 + orow + j;
        float v = acc[m][n][j] + bv;
        if (EPI == 0) {
          ((float*)Cout)[(long)bz * sC + (long)row * ldc + col] = v;
        } else if (EPI == 1) {
          u16 hi = f2bf(v);
          u16 lo = f2bf(v - bf2f(hi));
          u16* Co = (u16*)Cout + (long)bz * sC + (long)row * ldc;
          Co[col] = hi;
          Co[col + 1024] = lo;
        } else if (EPI == 2) {
          ((u16*)Cout)[(long)bz * sC + (long)row * ldc + col] = f2bf(v);
        } else {
          ((float*)Cout)[(long)bz * sC + (long)row * ldc + col] = tanhf(v);
        }
      }
    }
  }
}

// ---------- fp32 -> [hi|lo] bf16 pack (rows x 1024 -> rows x 2048) ----------
__global__ __launch_bounds__(256)
void split_pack(const float* __restrict__ X, u16* __restrict__ P,
                u16* __restrict__ FQ, long n4)
{
  long i = (long)blockIdx.x * 256 + threadIdx.x;
  const long stride = (long)gridDim.x * 256;
  for (; i < n4; i += stride) {
    float4 x = ((const float4*)X)[i];
    long e = i * 4;
    long row = e >> 10;
    int col = (int)(e & 1023);
    float xs[4] = {x.x, x.y, x.z, x.w};
    u16 h[4], l[4];
#pragma unroll
    for (int j = 0; j < 4; ++j) {
      h[j] = f2bf(xs[j]);
      l[j] = f2bf(xs[j] - bf2f(h[j]));
    }
    us4 hv = {h[0], h[1], h[2], h[3]};
    us4 lv = {l[0], l[1], l[2], l[3]};
    *(us4*)(P + row * 2048 + col) = hv;
    *(us4*)(P + row * 2048 + 1024 + col) = lv;
    if (FQ) *(us4*)(FQ + row * 2048 + 1024 + col) = hv;
  }
}

// ---------- values: [hi|lo] pack (row-major) + bf16 transpose ----------
__global__ __launch_bounds__(256)
void conv_values(const float* __restrict__ V, u16* __restrict__ Vp,
                 u16* __restrict__ VT)
{
  __shared__ u16 tile[64][68];
  const int b  = blockIdx.z;
  const int d0 = blockIdx.x * 64;
  const int k0 = blockIdx.y * 64;
  const int t  = threadIdx.x;
  const int tr = t >> 4;            // 0..15
  const int tc = (t & 15) * 4;      // 0..60
  const float* Vb = V + (long)b * (1024L * 1024);
  u16* Vpb = Vp + (long)b * (1024L * 2048);
  u16* VTb = VT + (long)b * (1024L * 1024);

#pragma unroll
  for (int i = 0; i < 4; ++i) {
    int k = tr + i * 16;
    float4 x = *(const float4*)(Vb + (long)(k0 + k) * 1024 + d0 + tc);
    float xs[4] = {x.x, x.y, x.z, x.w};
    u16 h[4], l[4];
#pragma unroll
    for (int j = 0; j < 4; ++j) {
      h[j] = f2bf(xs[j]);
      l[j] = f2bf(xs[j] - bf2f(h[j]));
      tile[k][tc + j] = h[j];
    }
    us4 hv = {h[0], h[1], h[2], h[3]};
    us4 lv = {l[0], l[1], l[2], l[3]};
    *(us4*)(Vpb + (long)(k0 + k) * 2048 + d0 + tc) = hv;
    *(us4*)(Vpb + (long)(k0 + k) * 2048 + 1024 + d0 + tc) = lv;
  }
  __syncthreads();
#pragma unroll
  for (int i = 0; i < 4; ++i) {
    int d = tr + i * 16;
    int k = tc;
    us4 o = {tile[k][d], tile[k + 1][d], tile[k + 2][d], tile[k + 3][d]};
    *(us4*)(VTb + (long)(d0 + d) * 1024 + k0 + k) = o;
  }
}

// ---------- plain fp32 -> bf16 cast ----------
__global__ __launch_bounds__(256)
void conv_cast(const float* __restrict__ X, u16* __restrict__ Y, long n4)
{
  long i = (long)blockIdx.x * 256 + threadIdx.x;
  const long stride = (long)gridDim.x * 256;
  for (; i < n4; i += stride) {
    float4 x = ((const float4*)X)[i];
    us4 o = {f2bf(x.x), f2bf(x.y), f2bf(x.z), f2bf(x.w)};
    *(us4*)(Y + i * 4) = o;
  }
}

// ---------- row softmax: fp32 scores[8192][1024] -> bf16 attn ----------
__global__ __launch_bounds__(256)
void softmax_rows(const float* __restrict__ S, u16* __restrict__ A)
{
  const long row = blockIdx.x;
  const float* src = S + row * 1024;
  const int t = threadIdx.x;
  const int lane = t & 63, wid = t >> 6;
  float4 v = ((const float4*)src)[t];
  float m = fmaxf(fmaxf(v.x, v.y), fmaxf(v.z, v.w));
#pragma unroll
  for (int off = 32; off >= 1; off >>= 1)
    m = fmaxf(m, __shfl_xor(m, off));
  __shared__ float redm[4];
  if (lane == 0) redm[wid] = m;
  __syncthreads();
  m = fmaxf(fmaxf(redm[0], redm[1]), fmaxf(redm[2], redm[3]));
  float e0 = __expf(v.x - m), e1 = __expf(v.y - m);
  float e2 = __expf(v.z - m), e3 = __expf(v.w - m);
  float s = e0 + e1 + e2 + e3;
#pragma unroll
  for (int off = 32; off >= 1; off >>= 1)
    s += __shfl_xor(s, off);
  __shared__ float reds[4];
  if (lane == 0) reds[wid] = s;
  __syncthreads();
  s = reds[0] + reds[1] + reds[2] + reds[3];
  float inv = 1.0f / s;
  us4 o = {f2bf(e0 * inv), f2bf(e1 * inv), f2bf(e2 * inv), f2bf(e3 * inv)};
  ((us4*)(A + row * 1024))[t] = o;
}

extern "C" void kernel_launch(void* const* d_in, const int* in_sizes, int n_in,
                              void* d_out, int out_size, void* d_ws, size_t ws_size,
                              hipStream_t stream)
{
  const float* query  = (const float*)d_in[0];  // [8,1024,1024]
  const float* values = (const float*)d_in[1];  // [8,1024,1024]
  const float* W1     = (const float*)d_in[2];  // [1024,1024]
  const float* b1     = (const float*)d_in[3];  // [1024]
  const float* W2     = (const float*)d_in[4];  // [1024,2048]
  const float* b2     = (const float*)d_in[5];  // [1024]
  float* out = (float*)d_out;                   // [8,1024,1024]

  char* ws = (char*)d_ws;
  const long MB = 1024L * 1024;
  // layout (152 MB total, with lifetime aliasing):
  u16*   W1p    = (u16*)(ws);              //   4 MB  W1 [hi|lo]
  u16*   W2b    = (u16*)(ws + 4 * MB);     //   4 MB  W2 bf16
  u16*   Aq     = (u16*)(ws + 8 * MB);     //  32 MB  query [hi|lo]   (dead after GEMM1)
  float* scores = (float*)(ws + 8 * MB);   //  32 MB  aliases Aq
  u16*   qr     = (u16*)(ws + 40 * MB);    //  32 MB  q_resize [hi|lo] (dead after GEMM2)
  u16*   attn   = (u16*)(ws + 40 * MB);    //  16 MB  aliases qr
  u16*   Vp     = (u16*)(ws + 72 * MB);    //  32 MB  values [hi|lo]
  u16*   VT     = (u16*)(ws + 104 * MB);   //  16 MB  values^T bf16
  u16*   feed   = (u16*)(ws + 120 * MB);   //  32 MB  [attended | query] bf16

  // conversions
  split_pack<<<dim3(2048), dim3(256), 0, stream>>>(query, Aq, feed, (8192L * 1024) / 4);
  split_pack<<<dim3(1024), dim3(256), 0, stream>>>(W1, W1p, (u16*)nullptr, (1024L * 1024) / 4);
  conv_values<<<dim3(16, 16, 8), dim3(256), 0, stream>>>(values, Vp, VT);
  conv_cast<<<dim3(1024), dim3(256), 0, stream>>>(W2, W2b, (1024L * 2048) / 4);

  // GEMM1: q_resize = query @ W1^T + b1  -> qr [hi|lo]   (hi/lo, virt-K=3072)
  gemm_bt<3, 1><<<dim3(256), dim3(512), 0, stream>>>(
      Aq, W1p, qr, b1, 1024, 2048, 2048, 2048, 0L, 0L, 0L, 32, 8);

  // GEMM2: scores[b] = qr[b] @ values[b]^T               (hi/lo, batched)
  gemm_bt<3, 0><<<dim3(256), dim3(512), 0, stream>>>(
      qr, Vp, scores, (const float*)nullptr, 1024, 2048, 2048, 1024,
      1024L * 2048, 1024L * 2048, 1024L * 1024, 4, 8);

  // softmax over keys -> bf16 attn
  softmax_rows<<<dim3(8192), dim3(256), 0, stream>>>(scores, attn);

  // GEMM3: attended[b] = attn[b] @ values[b] -> feed[:, 0:1024] bf16
  gemm_bt<1, 2><<<dim3(256), dim3(512), 0, stream>>>(
      attn, VT, feed, (const float*)nullptr, 1024, 1024, 1024, 2048,
      1024L * 1024, 1024L * 1024, 1024L * 2048, 4, 8);

  // GEMM4: out = tanh(feed @ W2^T + b2)
  gemm_bt<1, 3><<<dim3(256), dim3(512), 0, stream>>>(
      feed, W2b, out, b2, 2048, 2048, 2048, 1024, 0L, 0L, 0L, 32, 8);
}